// Round 10
// baseline (399.731 us; speedup 1.0000x reference)
//
#include <hip/hip_runtime.h>

// ---------------------------------------------------------------------------
// Two-layer GCN: out = Â(relu(Â(X W1) + b1) W2) + b2, Â = sym-norm adj + self loops
// Build: two-level bin sort, zero global atomics. Gather tables bf16,
// pre-scaled by dinv in GEMM epilogue: out = b + di*(G[i] + sum_e G[src_e]).
// R9->R10: aggregates were L2-CAPACITY-miss-bound (8-12.8MB tables vs 4MB/XCD
// L2 -> 94MB HBM fetch at ~1.75TB/s). Tables are now FEATURE-SLICED to <=4MB
// per slice (layer1: 4 x 16 feats, 32B rows; layer2: 2 x 20 feats, 40B rows);
// aggregation runs slice-by-slice (slice = blockIdx.x / bps, dispatch order
// keeps a slice's blocks temporally grouped) so gathers are L2-resident.
// GEMM epilogue emits the sliced layout directly.
// ---------------------------------------------------------------------------

__device__ inline float bflo(unsigned u) { return __uint_as_float(u << 16); }
__device__ inline float bfhi(unsigned u) { return __uint_as_float(u & 0xffff0000u); }
__device__ inline unsigned short f2bf(float x) {        // round-to-nearest-even
    unsigned u = __float_as_uint(x);
    return (unsigned short)((u + 0x7fff + ((u >> 16) & 1)) >> 16);
}

#define NBINS 256      // bins of 512 nodes: bin = dst >> 9
#define EPB   2048     // edges per block in pass 1

// ---- pass 1a: per-block histogram, transposed store -----------------------
__global__ __launch_bounds__(256) void p1_hist(const int* __restrict__ dst, int e,
                                               int nblk, int* __restrict__ hist_t) {
    __shared__ int h[NBINS];
    int tid = threadIdx.x;
    h[tid] = 0;
    __syncthreads();
    int base = blockIdx.x * EPB;
    #pragma unroll
    for (int j = 0; j < 8; ++j) {
        int idx = base + j * 256 + tid;
        if (idx < e) atomicAdd(&h[dst[idx] >> 9], 1);
    }
    __syncthreads();
    hist_t[tid * nblk + blockIdx.x] = h[tid];
}

// ---- 3-phase exclusive scan (chunk = 1024 per block) ----------------------
__global__ __launch_bounds__(256) void scan_a(const int* __restrict__ in, int* __restrict__ part,
                                              int* __restrict__ aux, int n) {
    __shared__ int lds[256];
    int tid = threadIdx.x;
    int base = blockIdx.x * 1024 + tid * 4;
    int v0 = (base + 0 < n) ? in[base + 0] : 0;
    int v1 = (base + 1 < n) ? in[base + 1] : 0;
    int v2 = (base + 2 < n) ? in[base + 2] : 0;
    int v3 = (base + 3 < n) ? in[base + 3] : 0;
    int s = v0 + v1 + v2 + v3;
    lds[tid] = s;
    __syncthreads();
    for (int off = 1; off < 256; off <<= 1) {
        int t = (tid >= off) ? lds[tid - off] : 0;
        __syncthreads();
        lds[tid] += t;
        __syncthreads();
    }
    int excl = lds[tid] - s;
    if (base + 0 < n) part[base + 0] = excl;
    if (base + 1 < n) part[base + 1] = excl + v0;
    if (base + 2 < n) part[base + 2] = excl + v0 + v1;
    if (base + 3 < n) part[base + 3] = excl + v0 + v1 + v2;
    if (tid == 255) aux[blockIdx.x] = lds[255];
}

__global__ __launch_bounds__(256) void scan_b(int* __restrict__ aux, int nb) {
    __shared__ int lds[256];
    int tid = threadIdx.x;
    int v = (tid < nb) ? aux[tid] : 0;
    lds[tid] = v;
    __syncthreads();
    for (int off = 1; off < 256; off <<= 1) {
        int t = (tid >= off) ? lds[tid - off] : 0;
        __syncthreads();
        lds[tid] += t;
        __syncthreads();
    }
    if (tid < nb) aux[tid] = lds[tid] - v;
}

__global__ __launch_bounds__(256) void scan_c(int* __restrict__ data,
                                              const int* __restrict__ aux, int n) {
    int i = blockIdx.x * blockDim.x + threadIdx.x;
    if (i < n) data[i] += aux[i >> 10];
}

// ---- pass 1b: scatter packed (src | local-dst) words grouped by bin -------
__global__ __launch_bounds__(256) void p1_scatter(const int* __restrict__ src,
                                                  const int* __restrict__ dst, int e,
                                                  int nblk, const int* __restrict__ off_t,
                                                  unsigned* __restrict__ ebuf) {
    __shared__ int cur[NBINS];
    int tid = threadIdx.x;
    cur[tid] = off_t[tid * nblk + blockIdx.x];
    __syncthreads();
    int base = blockIdx.x * EPB;
    #pragma unroll
    for (int j = 0; j < 8; ++j) {
        int idx = base + j * 256 + tid;
        if (idx < e) {
            int d = dst[idx];
            int p = atomicAdd(&cur[d >> 9], 1);
            ebuf[p] = (unsigned)src[idx] | ((unsigned)(d & 511) << 17);  // n < 2^17
        }
    }
}

// ---- pass 2: per-bin exact CSR (LDS count -> scan -> place) + dinv --------
__global__ __launch_bounds__(256) void p2_build(const unsigned* __restrict__ ebuf,
                                                const int* __restrict__ off_t,
                                                int nblk, int e, int n, int nbg,
                                                int* __restrict__ row_off,
                                                int* __restrict__ ssrc,
                                                float* __restrict__ dinv) {
    __shared__ int cnt[512];
    __shared__ int s1[256];
    __shared__ int loc[512];
    int tid = threadIdx.x;
    int g = blockIdx.x;
    int node0 = g << 9;
    int nlocal = n - node0; if (nlocal > 512) nlocal = 512;

    int segstart = off_t[g * nblk];
    int segend   = (g + 1 < NBINS) ? off_t[(g + 1) * nblk] : e;

    cnt[tid] = 0; cnt[tid + 256] = 0;
    __syncthreads();

    for (int i = segstart + tid; i < segend; i += 256)
        atomicAdd(&cnt[ebuf[i] >> 17], 1);
    __syncthreads();

    // exclusive scan of cnt[0..511] -> loc
    int a0 = cnt[2 * tid], a1 = cnt[2 * tid + 1];
    int sp = a0 + a1;
    s1[tid] = sp;
    __syncthreads();
    for (int off = 1; off < 256; off <<= 1) {
        int t = (tid >= off) ? s1[tid - off] : 0;
        __syncthreads();
        s1[tid] += t;
        __syncthreads();
    }
    int excl = s1[tid] - sp;
    loc[2 * tid]     = excl;
    loc[2 * tid + 1] = excl + a0;
    __syncthreads();

    // emit row_off + dinv (coalesced)
    for (int l = tid; l < nlocal; l += 256) {
        row_off[node0 + l] = segstart + loc[l];
        dinv[node0 + l] = rsqrtf((float)cnt[l] + 1.0f);   // +1 = self loop
    }
    if (g == nbg - 1 && tid == 0) row_off[n] = segend;
    __syncthreads();

    // place: loc doubles as cursor (old value = local offset)
    for (int i = segstart + tid; i < segend; i += 256) {
        unsigned p = ebuf[i];
        int r = atomicAdd(&loc[p >> 17], 1);
        ssrc[segstart + r] = (int)(p & 0x1FFFFu);
    }
}

// ---- GEMM G = bf16(dinv * (X W)): K-chunked LDS staging, register-tiled ---
// 64x64 block tile, 4x4/thread, stride-16 mapping, K in 32-wide chunks.
// Epilogue writes FEATURE-SLICED layout: col cc -> slice cc/SF, local cc%SF;
// slice s base = s * n * SF (ushorts).
template <int K, int M, int SF>
__global__ __launch_bounds__(256) void gemm_xw(const float* __restrict__ X,
                                               const float* __restrict__ W,
                                               const float* __restrict__ dinv,
                                               unsigned short* __restrict__ G, int n) {
    constexpr int GQ = 8;            // float4 granules per 32-wide chunk
    constexpr int SG = GQ + 1;       // padded stride (odd)
    __shared__ float4 xs[64 * SG];
    __shared__ float4 wt[64 * SG];

    const int tid = threadIdx.x;
    const int r0  = blockIdx.x * 64;
    const int tc  = tid & 15;
    const int tr  = tid >> 4;

    const int srow0 = tid >> 3, skq0 = tid & 7;
    const int srow1 = (tid + 256) >> 3, skq1 = tid & 7;
    int rr0 = r0 + srow0; rr0 = rr0 < n ? rr0 : n - 1;
    int rr1 = r0 + srow1; rr1 = rr1 < n ? rr1 : n - 1;

    float acc[4][4];
    #pragma unroll
    for (int i = 0; i < 4; ++i)
        #pragma unroll
        for (int j = 0; j < 4; ++j) acc[i][j] = 0.f;

    for (int kc = 0; kc < K; kc += 32) {
        __syncthreads();
        xs[srow0 * SG + skq0] = *reinterpret_cast<const float4*>(&X[(size_t)rr0 * K + kc + skq0 * 4]);
        xs[srow1 * SG + skq1] = *reinterpret_cast<const float4*>(&X[(size_t)rr1 * K + kc + skq1 * 4]);
        {
            int m = srow0, kq = skq0;
            float4 v = make_float4(0.f, 0.f, 0.f, 0.f);
            if (m < M) {
                int k = kc + kq * 4;
                v.x = W[(k + 0) * M + m]; v.y = W[(k + 1) * M + m];
                v.z = W[(k + 2) * M + m]; v.w = W[(k + 3) * M + m];
            }
            wt[m * SG + kq] = v;
            m = srow1; kq = skq1;
            float4 u = make_float4(0.f, 0.f, 0.f, 0.f);
            if (m < M) {
                int k = kc + kq * 4;
                u.x = W[(k + 0) * M + m]; u.y = W[(k + 1) * M + m];
                u.z = W[(k + 2) * M + m]; u.w = W[(k + 3) * M + m];
            }
            wt[m * SG + kq] = u;
        }
        __syncthreads();

        #pragma unroll 2
        for (int kq = 0; kq < GQ; ++kq) {
            float4 xv[4], wv[4];
            #pragma unroll
            for (int i = 0; i < 4; ++i) xv[i] = xs[(tr + 16 * i) * SG + kq];
            #pragma unroll
            for (int j = 0; j < 4; ++j) wv[j] = wt[(tc + 16 * j) * SG + kq];
            #pragma unroll
            for (int i = 0; i < 4; ++i)
                #pragma unroll
                for (int j = 0; j < 4; ++j) {
                    acc[i][j] = fmaf(xv[i].x, wv[j].x, acc[i][j]);
                    acc[i][j] = fmaf(xv[i].y, wv[j].y, acc[i][j]);
                    acc[i][j] = fmaf(xv[i].z, wv[j].z, acc[i][j]);
                    acc[i][j] = fmaf(xv[i].w, wv[j].w, acc[i][j]);
                }
        }
    }

    #pragma unroll
    for (int i = 0; i < 4; ++i) {
        int row = r0 + tr + 16 * i;
        if (row < n) {
            float di = dinv[row];
            #pragma unroll
            for (int j = 0; j < 4; ++j) {
                int cc = tc + 16 * j;
                if (cc < M) {
                    int s  = cc / SF;
                    int lc = cc - s * SF;
                    G[(size_t)s * n * SF + (size_t)row * SF + lc] = f2bf(di * acc[i][j]);
                }
            }
        }
    }
}

// ---- Sliced aggregation, layer 1 (16 feats/slice, 8 uints = 32B rows) -----
// slice = blockIdx.x / bps (dispatch order groups slices -> slice L2-resident)
// 8 groups x 8 lanes; lane owns feats {2c,2c+1}; 2-deep unroll, 16 edges in
// flight. Reduce via shfl_xor 8|16|32.
template <bool RELU>
__global__ __launch_bounds__(256) void aggregate64s(const unsigned* __restrict__ G,
                                                    const float* __restrict__ dinv,
                                                    const int* __restrict__ row_off,
                                                    const int* __restrict__ ssrc,
                                                    const float* __restrict__ bias,
                                                    float* __restrict__ out, int n) {
    int bps   = (n + 3) >> 2;                      // blocks per slice
    int slice = blockIdx.x / bps;
    int blk   = blockIdx.x - slice * bps;
    int wid   = (blk * 256 + (int)threadIdx.x) >> 6;
    if (wid >= n) return;
    int lane = threadIdx.x & 63;
    int g = lane >> 3;                             // 0..7: edge group
    int c = lane & 7;                              // uint slot (feats 2c,2c+1)
    const unsigned* __restrict__ Gs = G + (size_t)slice * n * 8;

    float2 acc = make_float2(0.f, 0.f);
    int e0 = row_off[wid], e1 = row_off[wid + 1];
    int e = e0 + g;
    for (; e + 8 < e1; e += 16) {                  // 2 edges per group per iter
        int s0 = ssrc[e], s1 = ssrc[e + 8];
        unsigned u0 = Gs[(size_t)s0 * 8 + c];
        unsigned u1 = Gs[(size_t)s1 * 8 + c];
        acc.x += bflo(u0); acc.y += bfhi(u0);
        acc.x += bflo(u1); acc.y += bfhi(u1);
    }
    if (e < e1) {
        unsigned u = Gs[(size_t)ssrc[e] * 8 + c];
        acc.x += bflo(u); acc.y += bfhi(u);
    }

    acc.x += __shfl_xor(acc.x, 8);  acc.y += __shfl_xor(acc.y, 8);
    acc.x += __shfl_xor(acc.x, 16); acc.y += __shfl_xor(acc.y, 16);
    acc.x += __shfl_xor(acc.x, 32); acc.y += __shfl_xor(acc.y, 32);

    float di = dinv[wid];
    unsigned us = Gs[(size_t)wid * 8 + c];         // self loop
    float2 bv = ((const float2*)bias)[slice * 8 + c];
    float2 o;
    o.x = fmaf(di, acc.x + bflo(us), bv.x);
    o.y = fmaf(di, acc.y + bfhi(us), bv.y);
    if (RELU) { o.x = fmaxf(o.x, 0.f); o.y = fmaxf(o.y, 0.f); }
    if (g == 0) ((float2*)out)[(size_t)wid * 32 + slice * 8 + c] = o;
}

// ---- Sliced aggregation, layer 2 (20 feats/slice, 10 uints = 40B rows) ----
// 4 groups x 16 lanes (10 active on loads); 4-deep unroll, 16 edges in flight.
// Reduce via shfl_xor 16|32.
template <bool RELU>
__global__ __launch_bounds__(256) void aggregate40s(const unsigned* __restrict__ G,
                                                    const float* __restrict__ dinv,
                                                    const int* __restrict__ row_off,
                                                    const int* __restrict__ ssrc,
                                                    const float* __restrict__ bias,
                                                    float* __restrict__ out, int n) {
    int bps   = (n + 3) >> 2;
    int slice = blockIdx.x / bps;
    int blk   = blockIdx.x - slice * bps;
    int wid   = (blk * 256 + (int)threadIdx.x) >> 6;
    if (wid >= n) return;
    int lane = threadIdx.x & 63;
    int g = lane >> 4;                             // 0..3: edge group
    int c = lane & 15;
    int cc = c < 10 ? c : 9;                       // clamp: stay in bounds
    const unsigned* __restrict__ Gs = G + (size_t)slice * n * 10;

    float2 acc = make_float2(0.f, 0.f);
    int e0 = row_off[wid], e1 = row_off[wid + 1];
    int e = e0 + g;
    for (; e + 12 < e1; e += 16) {                 // 4 edges per group per iter
        int s0 = ssrc[e], s1 = ssrc[e + 4], s2 = ssrc[e + 8], s3 = ssrc[e + 12];
        unsigned u0 = Gs[(size_t)s0 * 10 + cc];
        unsigned u1 = Gs[(size_t)s1 * 10 + cc];
        unsigned u2 = Gs[(size_t)s2 * 10 + cc];
        unsigned u3 = Gs[(size_t)s3 * 10 + cc];
        acc.x += bflo(u0); acc.y += bfhi(u0);
        acc.x += bflo(u1); acc.y += bfhi(u1);
        acc.x += bflo(u2); acc.y += bfhi(u2);
        acc.x += bflo(u3); acc.y += bfhi(u3);
    }
    for (; e < e1; e += 4) {
        unsigned u = Gs[(size_t)ssrc[e] * 10 + cc];
        acc.x += bflo(u); acc.y += bfhi(u);
    }

    acc.x += __shfl_xor(acc.x, 16); acc.y += __shfl_xor(acc.y, 16);
    acc.x += __shfl_xor(acc.x, 32); acc.y += __shfl_xor(acc.y, 32);

    float di = dinv[wid];
    unsigned us = Gs[(size_t)wid * 10 + cc];       // self loop
    float2 bv = ((const float2*)bias)[slice * 10 + cc];
    float2 o;
    o.x = fmaf(di, acc.x + bflo(us), bv.x);
    o.y = fmaf(di, acc.y + bfhi(us), bv.y);
    if (RELU) { o.x = fmaxf(o.x, 0.f); o.y = fmaxf(o.y, 0.f); }
    if (g == 0 && c < 10) ((float2*)out)[(size_t)wid * 20 + slice * 10 + c] = o;
}

// ---------------------------------------------------------------------------
extern "C" void kernel_launch(void* const* d_in, const int* in_sizes, int n_in,
                              void* d_out, int out_size, void* d_ws, size_t ws_size,
                              hipStream_t stream) {
    const float* x  = (const float*)d_in[0];
    const int*   ei = (const int*)d_in[1];
    const float* W1 = (const float*)d_in[2];
    const float* b1 = (const float*)d_in[3];
    const float* W2 = (const float*)d_in[4];
    const float* b2 = (const float*)d_in[5];

    const int gnn_f = in_sizes[3];            // 64
    const int out_f = in_sizes[5];            // 40
    const int in_f  = in_sizes[2] / gnn_f;    // 128
    const int e     = in_sizes[1] / 2;        // 1,600,000
    const int n     = in_sizes[0] / in_f;     // 100,000 (< 2^17, required by packing)

    const int* src = ei;
    const int* dst = ei + e;

    const int nblk   = (e + EPB - 1) / EPB;               // pass-1 blocks (782)
    const int nscan  = NBINS * nblk;                      // 200,192
    const int nbg    = (n + 511) / 512;                   // pass-2 bins (196)
    const int nchunks = (nscan + 1023) / 1024;            // 196 (<= 256)
    const int bps    = (n + 3) / 4;                       // agg blocks per slice

    // ---- workspace partition (256B aligned) ----
    char* base = (char*)d_ws;
    size_t off = 0;
    auto alloc = [&](size_t bytes) -> char* {
        char* p = base + off;
        off = (off + bytes + 255) & ~(size_t)255;
        return p;
    };
    int*            hist_t  = (int*)            alloc((size_t)nscan * 4);
    int*            off_t   = (int*)            alloc((size_t)nscan * 4);
    int*            aux     = (int*)            alloc(256 * 4);
    unsigned*       ebuf    = (unsigned*)       alloc((size_t)e * 4);
    int*            row_off = (int*)            alloc((size_t)(n + 1) * 4);
    int*            ssrc    = (int*)            alloc((size_t)e * 4);
    float*          dinv    = (float*)          alloc((size_t)n * 4);
    unsigned short* g1      = (unsigned short*) alloc((size_t)n * gnn_f * 2);
    float*          a1      = (float*)          alloc((size_t)n * gnn_f * 4);
    unsigned short* g2      = (unsigned short*) alloc((size_t)n * out_f * 2);
    (void)ws_size;

    // build: histogram -> scan -> scatter packed words -> per-bin CSR
    p1_hist<<<nblk, 256, 0, stream>>>(dst, e, nblk, hist_t);
    scan_a<<<nchunks, 256, 0, stream>>>(hist_t, off_t, aux, nscan);
    scan_b<<<1, 256, 0, stream>>>(aux, nchunks);
    scan_c<<<(nscan + 255) / 256, 256, 0, stream>>>(off_t, aux, nscan);
    p1_scatter<<<nblk, 256, 0, stream>>>(src, dst, e, nblk, off_t, ebuf);
    p2_build<<<nbg, 256, 0, stream>>>(ebuf, off_t, nblk, e, n, nbg, row_off, ssrc, dinv);

    // layer 1: g1 = bf16(dinv * (x@W1)) sliced ; a1 = relu(di*(g1[i]+sum g1[s]) + b1)
    gemm_xw<128, 64, 16><<<(n + 63) / 64, 256, 0, stream>>>(x, W1, dinv, g1, n);
    aggregate64s<true><<<4 * bps, 256, 0, stream>>>((const unsigned*)g1, dinv, row_off, ssrc, b1, a1, n);

    // layer 2: g2 = bf16(dinv * (a1@W2)) sliced ; out = di*(g2[i]+sum g2[s]) + b2
    gemm_xw<64, 40, 20><<<(n + 63) / 64, 256, 0, stream>>>(a1, W2, dinv, g2, n);
    aggregate40s<false><<<2 * bps, 256, 0, stream>>>((const unsigned*)g2, dinv, row_off, ssrc, b2, (float*)d_out, n);
}